// Round 19
// baseline (128.169 us; speedup 1.0000x reference)
//
#include <hip/hip_runtime.h>
#include <hip/hip_bf16.h>

#define N_ 32
#define C_ 128
#define H_ 56
#define W_ 56
#define K_ 256
#define HW_ (H_*W_)
#define HP_ 58     // padded spatial dim
#define NG_ 36     // 4 channel-quarters x 9 taps
#define COLS_ 464  // window: 8 xp rows x 58 cols
#define PLANE_ 468 // plane stride in 16B units (468*4 dwords % 32 = 16 banks)

typedef __attribute__((ext_vector_type(8))) __bf16 bf16x8;
typedef __attribute__((ext_vector_type(8))) unsigned short ushort8;
typedef __attribute__((ext_vector_type(4))) float f32x4;
typedef __attribute__((ext_vector_type(16))) float f32x16;

typedef __attribute__((address_space(1))) const unsigned int g1_u32;
typedef __attribute__((address_space(3))) unsigned int l3_u32;

__device__ __forceinline__ void dma16(const void* g, void* l) {
    __builtin_amdgcn_global_load_lds((g1_u32*)g, (l3_u32*)l, 16, 0, 0);
}

__device__ __forceinline__ unsigned short f2bf(float f) {
    unsigned int u = __builtin_bit_cast(unsigned int, f);
    u += 0x7FFFu + ((u >> 16) & 1u);   // round-to-nearest-even
    return (unsigned short)(u >> 16);
}

// ------- weight repack for 32x32x16 fragments (R14-verified mapping) -------
// element o = ((g*2 + kk)*8 + mt)*512 + lane*8 + j
//   g = q*9 + tap ; kout = mt*32 + (lane&31) ; c = q*32 + kk*16 + (lane>>5)*8 + j
__global__ void repack_w5_kernel(const float* __restrict__ w,
                                 unsigned short* __restrict__ wp5) {
    int o = blockIdx.x * 256 + threadIdx.x;
    if (o >= NG_ * 2 * 8 * 512) return;
    int j    = o & 7;
    int lane = (o >> 3) & 63;
    int mt   = (o >> 9) & 7;
    int kk   = (o >> 12) & 1;
    int g    = o >> 13;
    int q    = g / 9;
    int tap  = g - q * 9;
    int kout = mt * 32 + (lane & 31);
    int c    = q * 32 + kk * 16 + (lane >> 5) * 8 + j;
    wp5[o] = f2bf(w[(kout * C_ + c) * 9 + tap]);
}

// ---------------- x prepack: NCHW fp32 -> padded NHWC bf16 -----------------
__global__ void pack_x_kernel(const float* __restrict__ x,
                              unsigned short* __restrict__ xp) {
    __shared__ unsigned short Lt[128 * 57];
    const int t  = threadIdx.x;               // 256
    const int b  = blockIdx.x;                // n*58 + hp
    const int n  = b / HP_;
    const int hp = b - n * HP_;
    unsigned short* orow = xp + ((size_t)(n * HP_ + hp) * HP_) * 128;

    ushort8 z = {0, 0, 0, 0, 0, 0, 0, 0};
    if (hp == 0 || hp == HP_ - 1) {
        for (int u = t; u < 928; u += 256)
            *(ushort8*)(orow + u * 8) = z;
        return;
    }
    const int h = hp - 1;
    const float* src = x + ((size_t)n * C_ * HW_ + h * W_);
    #pragma unroll
    for (int k = 0; k < 28; ++k) {
        int idx = k * 256 + t;
        int c = idx / 56, w2 = idx - 56 * c;
        Lt[c * 57 + w2] = f2bf(src[c * HW_ + w2]);
    }
    __syncthreads();
    for (int u = t; u < 928; u += 256) {
        int wp = u >> 4, c8 = u & 15;
        ushort8 v = z;
        if (wp >= 1 && wp <= 56) {
            #pragma unroll
            for (int j = 0; j < 8; ++j)
                v[j] = Lt[(c8 * 8 + j) * 57 + (wp - 1)];
        }
        *(ushort8*)(orow + u * 8) = v;
    }
}

// ---------------- main conv: 32x32 frags, B-reuse=2, window-chunk ----------
// Block: 256 kout x 128 flat px, 1024 thr / 16 waves as 4M x 4N:
// wave = 64 kout x 32 px (mi=2, ni=1, kk=2; acc = 2 x f32x16 = 32 regs;
// each B-fragment feeds 2 MFMAs -> LDS port 13.8k cy/block < matrix 18.4k:
// matrix-bound). Window = 8 consecutive xp rows x 32 ch, plane-major
// [slot(4)][col(464..468)], realized by linear DMA dest + source computed
// from (slot = u/PLANE_, col = u%PLANE_). Reads: 32-lane halves are
// consecutive 512B runs -> conflict-free (R14-measured 0). Ring-2, staged
// once per cc-chunk; 9 taps at additive offsets; A parity-prefetch from L2;
// counted vmcnt(4); 3 in-loop barriers; setprio.
__launch_bounds__(1024, 4)
__global__ void conv_mfma18_kernel(const unsigned short* __restrict__ xp,
                                   const unsigned short* __restrict__ wp5,
                                   const float* __restrict__ bias,
                                   float* __restrict__ out) {
    __shared__ __align__(16) unsigned char Bl[2][2048 * 16];   // 64 KB

    const int t    = threadIdx.x;
    const int lane = t & 63;
    const int wid  = t >> 6;     // 0..15
    const int mt2  = wid >> 2;   // 64-kout group 0..3
    const int nw   = wid & 3;    // 32-px quarter 0..3
    const int l5   = lane >> 5;  // k-subgroup 0..1
    const int lc   = lane & 31;  // col/row-in-fragment

    // bijective XCD swizzle (784 % 8 == 0): 98 contiguous blocks per XCD
    const int b    = blockIdx.x;
    const int orig = (b & 7) * 98 + (b >> 3);
    const int px0  = orig * 128;

    // window base row (global padded row index; rows contiguous across images)
    const int n0 = px0 / HW_;
    const int h0 = (px0 - n0 * HW_) / W_;
    const int G0 = n0 * HP_ + h0;

    // per-lane B column base (tap adds r*58 + s)
    int cbase;
    {
        int px = px0 + nw * 32 + lc;
        int n  = px / HW_;
        int pr = px - n * HW_;
        int h  = pr / W_;
        int w2 = pr - W_ * h;
        cbase = (n * HP_ + h - G0) * HP_ + w2;
    }

    // B read byte offsets: plane = kk*2 + l5
    int bunit[2];
    #pragma unroll
    for (int kk = 0; kk < 2; ++kk)
        bunit[kk] = ((kk * 2 + l5) * PLANE_ + cbase) * 16;

    // staging: 2 DMAs/thread; dest unit u (linear) realizes [slot][col]
    // via source computed from slot = u/PLANE_, col = u%PLANE_.
    const unsigned short* bsrc[2];
    #pragma unroll
    for (int i = 0; i < 2; ++i) {
        int u    = i * 1024 + t;
        int slot = u / PLANE_;                 // 0..4
        int col  = u - slot * PLANE_;
        bool ok  = (slot < 4) && (col < COLS_);
        int ssl  = ok ? slot : 0;
        int scol = ok ? col : 0;
        long sidx = (long)G0 * HP_ + scol;
        if (sidx > (long)N_ * HP_ * HP_ - 1) sidx = 0;   // never-read clamp
        bsrc[i] = xp + (size_t)sidx * 128 + ssl * 8;
    }

    const ushort8* W8 = (const ushort8*)wp5;

    f32x16 acc[2];
    #pragma unroll
    for (int mi = 0; mi < 2; ++mi)
        #pragma unroll
        for (int r = 0; r < 16; ++r)
            acc[mi][r] = 0.f;

    bf16x8 areg[2][2][2];   // [parity][kk][mi]

#define STAGE(CC, BUF)                                                      \
    {                                                                       \
        dma16(bsrc[0] + (CC) * 32, Bl[BUF] + (size_t)t * 16);               \
        dma16(bsrc[1] + (CC) * 32, Bl[BUF] + (size_t)(1024 + t) * 16);      \
    }

#define LOAD_A(G, PAR)                                                      \
    _Pragma("unroll")                                                       \
    for (int kk = 0; kk < 2; ++kk)                                          \
        _Pragma("unroll")                                                   \
        for (int mi = 0; mi < 2; ++mi)                                      \
            areg[PAR][kk][mi] = __builtin_bit_cast(bf16x8,                  \
                W8[(((G) * 2 + kk) * 8 + (mt2 * 2 + mi)) * 64 + lane]);

    // prologue
    LOAD_A(0, 0)
    STAGE(0, 0)
    asm volatile("s_waitcnt vmcnt(0)" ::: "memory");
    __builtin_amdgcn_s_barrier();

    #pragma unroll
    for (int cc = 0; cc < 4; ++cc) {
        const int cur = cc & 1;

        if (cc < 3) { STAGE(cc + 1, cur ^ 1) }   // lands under 9-tap sequence

        #pragma unroll
        for (int tap = 0; tap < 9; ++tap) {
            const int g  = cc * 9 + tap;
            const int p  = g & 1;
            const int r_ = tap / 3;
            const int s_ = tap - 3 * r_;
            const int SH = (r_ * HP_ + s_) * 16;

            bf16x8 bb[2];
            #pragma unroll
            for (int kk = 0; kk < 2; ++kk)
                bb[kk] = __builtin_bit_cast(bf16x8,
                    *(const ushort8*)(Bl[cur] + bunit[kk] + SH));

            if (g + 1 < NG_) {
                LOAD_A(g + 1, p ^ 1)
            }

            __builtin_amdgcn_s_setprio(1);
            #pragma unroll
            for (int kk = 0; kk < 2; ++kk)
                #pragma unroll
                for (int mi = 0; mi < 2; ++mi)
                    acc[mi] = __builtin_amdgcn_mfma_f32_32x32x16_bf16(
                        areg[p][kk][mi], bb[kk], acc[mi], 0, 0, 0);
            __builtin_amdgcn_s_setprio(0);
        }

        if (cc < 3) {
            asm volatile("s_waitcnt vmcnt(4)" ::: "memory");   // keep A quad
            __builtin_amdgcn_s_barrier();
        }
    }
#undef STAGE
#undef LOAD_A

    // epilogue: C/D 32x32 (R14-verified): col(px)=lane&31,
    // row(kout) = (r&3) + 8*(r>>2) + 4*(lane>>5)
    {
        int px = px0 + nw * 32 + lc;
        int n2 = px / HW_;
        int pr = px - n2 * HW_;
        float* ob = out + (size_t)n2 * K_ * HW_ + pr;
        #pragma unroll
        for (int mi = 0; mi < 2; ++mi) {
            const int kb = (mt2 * 2 + mi) * 32;
            #pragma unroll
            for (int r = 0; r < 16; ++r) {
                int kout = kb + (r & 3) + 8 * (r >> 2) + 4 * l5;
                ob[(size_t)kout * HW_] = acc[mi][r] + bias[kout];
            }
        }
    }
}

// ---------------- fallback (reg-staged fp32 path, no workspace xp) ---------
__global__ void repack_w2_kernel(const float* __restrict__ w,
                                 unsigned short* __restrict__ wp2) {
    int o = blockIdx.x * 256 + threadIdx.x;
    if (o >= 9 * 16 * 4 * 64 * 8) return;
    int j   = o & 7;
    int l   = (o >> 3) & 63;
    int cc  = (o >> 9) & 3;
    int kg  = (o >> 11) & 15;
    int tap = o >> 15;
    int k = kg * 16 + (l & 15);
    int c = cc * 32 + (l >> 4) * 8 + j;
    wp2[o] = f2bf(w[(k * C_ + c) * 9 + tap]);
}

__launch_bounds__(256, 2)
__global__ void conv_mfma3_kernel(const float* __restrict__ x,
                                  const unsigned short* __restrict__ wp2,
                                  const float* __restrict__ bias,
                                  float* __restrict__ out) {
    __shared__ unsigned short Xt[2][232 * 40];
    const int t    = threadIdx.x;
    const int lane = t & 63;
    const int wid  = t >> 6;
    const int b    = blockIdx.x;
    const int orig = (b & 7) * 112 + (b >> 3);
    const int n    = orig / 28;
    const int rp   = orig - n * 28;
    const int h0   = rp * 2;
    const int lp = lane & 15;
    const int lk = lane >> 4;
    int bofs[7];
    #pragma unroll
    for (int ni = 0; ni < 7; ++ni) {
        int p  = ni * 16 + lp;
        int hr = (p >= 56) ? 1 : 0;
        int pw = p - hr * 56;
        bofs[ni] = (hr * 58 + pw) * 40 + lk * 8;
    }
    bool  ok[4], v928[4];
    const float* xq[4];
    int   ldsw[4];
    #pragma unroll
    for (int i = 0; i < 4; ++i) {
        int it = i * 256 + t;
        v928[i] = (it < 928);
        int itc  = v928[i] ? it : 0;
        int csub = (itc >= 232) + (itc >= 464) + (itc >= 696);
        int col  = itc - 232 * csub;
        int hh   = col / 58;
        int ww   = col - 58 * hh;
        int hin  = h0 + hh - 1;
        int win  = ww - 1;
        ok[i]   = v928[i] && (unsigned)hin < 56u && (unsigned)win < 56u;
        xq[i]   = x + (((n * C_ + csub * 8) * H_ + hin) * W_ + win);
        ldsw[i] = col * 40 + csub * 8;
    }
    float xv[4][8];
#define STAGE_LOAD(CH)                                                 \
    _Pragma("unroll")                                                  \
    for (int i = 0; i < 4; ++i)                                        \
        _Pragma("unroll")                                              \
        for (int j = 0; j < 8; ++j)                                    \
            xv[i][j] = ok[i] ? xq[i][((CH) * 32 + j) * HW_] : 0.f;
#define STAGE_WRITE(BUF)                                               \
    _Pragma("unroll")                                                  \
    for (int i = 0; i < 4; ++i)                                        \
        if (v928[i]) {                                                 \
            ushort8 v;                                                 \
            _Pragma("unroll")                                          \
            for (int j = 0; j < 8; ++j) v[j] = f2bf(xv[i][j]);         \
            *(ushort8*)(&Xt[BUF][ldsw[i]]) = v;                        \
        }
    f32x4 acc[4][7];
    #pragma unroll
    for (int mi = 0; mi < 4; ++mi)
        #pragma unroll
        for (int ni = 0; ni < 7; ++ni)
            acc[mi][ni] = (f32x4){0.f, 0.f, 0.f, 0.f};
    STAGE_LOAD(0)
    STAGE_WRITE(0)
    __syncthreads();
    const ushort8* W8 = (const ushort8*)wp2;
    for (int cc = 0; cc < 4; ++cc) {
        const int cur = cc & 1;
        if (cc < 3) { STAGE_LOAD(cc + 1) }
        const int tb = wid * 1024 + cc * 64 + lane;
        #pragma unroll
        for (int tap = 0; tap < 9; ++tap) {
            const int r    = tap / 3;
            const int s    = tap - 3 * r;
            const int toff = (r * 58 + s) * 40;
            bf16x8 a[4];
            #pragma unroll
            for (int mi = 0; mi < 4; ++mi)
                a[mi] = __builtin_bit_cast(bf16x8, W8[tap * 4096 + tb + mi * 256]);
            bf16x8 bfr[7];
            #pragma unroll
            for (int ni = 0; ni < 7; ++ni)
                bfr[ni] = __builtin_bit_cast(bf16x8,
                    *(const ushort8*)(&Xt[cur][bofs[ni] + toff]));
            #pragma unroll
            for (int ni = 0; ni < 7; ++ni)
                #pragma unroll
                for (int mi = 0; mi < 4; ++mi)
                    acc[mi][ni] = __builtin_amdgcn_mfma_f32_16x16x32_bf16(
                        a[mi], bfr[ni], acc[mi][ni], 0, 0, 0);
        }
        if (cc < 3) {
            STAGE_WRITE(cur ^ 1)
            __syncthreads();
        }
    }
    #pragma unroll
    for (int mi = 0; mi < 4; ++mi) {
        #pragma unroll
        for (int j = 0; j < 4; ++j) {
            int kout = wid * 64 + mi * 16 + lk * 4 + j;
            float bv = bias[kout];
            float* op = out + ((n * K_ + kout) * H_ + h0) * W_;
            #pragma unroll
            for (int ni = 0; ni < 7; ++ni) {
                int p  = ni * 16 + lp;
                int hr = (p >= 56) ? 1 : 0;
                int pw = p - hr * 56;
                op[hr * W_ + pw] = acc[mi][ni][j] + bv;
            }
        }
    }
#undef STAGE_LOAD
#undef STAGE_WRITE
}

__global__ void conv_naive_kernel(const float* __restrict__ x,
                                  const float* __restrict__ w,
                                  const float* __restrict__ b,
                                  float* __restrict__ out) {
    int idx = blockIdx.x * 256 + threadIdx.x;
    if (idx >= N_ * K_ * HW_) return;
    int pw = idx % 56; int tmp = idx / 56;
    int h  = tmp % 56; tmp /= 56;
    int k  = tmp % 256; int n = tmp / 256;
    float acc = b[k];
    for (int c = 0; c < C_; ++c)
        for (int r = 0; r < 3; ++r) {
            int hin = h + r - 1;
            if ((unsigned)hin >= 56u) continue;
            for (int s = 0; s < 3; ++s) {
                int win = pw + s - 1;
                if ((unsigned)win >= 56u) continue;
                acc += x[((n * C_ + c) * H_ + hin) * W_ + win] * w[(k * C_ + c) * 9 + r * 3 + s];
            }
        }
    out[idx] = acc;
}

extern "C" void kernel_launch(void* const* d_in, const int* in_sizes, int n_in,
                              void* d_out, int out_size, void* d_ws, size_t ws_size,
                              hipStream_t stream) {
    const float* x = (const float*)d_in[0];
    const float* w = (const float*)d_in[1];
    const float* b = (const float*)d_in[2];
    float* out = (float*)d_out;

    const size_t xp_bytes = (size_t)N_ * HP_ * HP_ * C_ * 2;              // 27,557,888
    const size_t wp_bytes = (size_t)NG_ * 2 * 8 * 512 * 2;                // 589,824

    if (ws_size >= xp_bytes + wp_bytes) {
        unsigned short* xpad = (unsigned short*)d_ws;
        unsigned short* wp5  = (unsigned short*)((char*)d_ws + xp_bytes);
        pack_x_kernel<<<N_ * HP_, 256, 0, stream>>>(x, xpad);
        repack_w5_kernel<<<(NG_ * 2 * 8 * 512 + 255) / 256, 256, 0, stream>>>(w, wp5);
        conv_mfma18_kernel<<<784, 1024, 0, stream>>>(xpad, wp5, b, out);
    } else if (ws_size >= wp_bytes) {
        unsigned short* wp2 = (unsigned short*)d_ws;
        repack_w2_kernel<<<(9 * 16 * 4 * 64 * 8 + 255) / 256, 256, 0, stream>>>(w, wp2);
        conv_mfma3_kernel<<<896, 256, 0, stream>>>(x, wp2, b, out);
    } else {
        conv_naive_kernel<<<(N_ * K_ * HW_ + 255) / 256, 256, 0, stream>>>(x, w, b, out);
    }
}

// Round 20
// 108.888 us; speedup vs baseline: 1.1771x; 1.1771x over previous
//
#include <hip/hip_runtime.h>
#include <hip/hip_bf16.h>

#define N_ 32
#define C_ 128
#define H_ 56
#define W_ 56
#define K_ 256
#define HW_ (H_*W_)
#define HP_ 58     // padded spatial dim
#define NG_ 36     // 4 channel-quarters x 9 taps
#define COLS_ 464  // window: 8 xp rows x 58 cols
#define PLANE_ 468 // plane stride in 16B units
#define MAXROW_ 107647  // N_*HP_*HP_ - 1

typedef __attribute__((ext_vector_type(8))) __bf16 bf16x8;
typedef __attribute__((ext_vector_type(8))) unsigned short ushort8;
typedef __attribute__((ext_vector_type(4))) float f32x4;
typedef __attribute__((ext_vector_type(16))) float f32x16;

typedef __attribute__((address_space(1))) const unsigned int g1_u32;
typedef __attribute__((address_space(3))) unsigned int l3_u32;

__device__ __forceinline__ void dma16(const void* g, void* l) {
    __builtin_amdgcn_global_load_lds((g1_u32*)g, (l3_u32*)l, 16, 0, 0);
}

__device__ __forceinline__ unsigned short f2bf(float f) {
    unsigned int u = __builtin_bit_cast(unsigned int, f);
    u += 0x7FFFu + ((u >> 16) & 1u);   // round-to-nearest-even
    return (unsigned short)(u >> 16);
}

// ------- weight repack for 32x32x16 fragments (R14/R19-verified) -----------
// element o = ((g*2 + kk)*8 + mt)*512 + lane*8 + j
//   g = q*9 + tap ; kout = mt*32 + (lane&31) ; c = q*32 + kk*16 + (lane>>5)*8 + j
__global__ void repack_w5_kernel(const float* __restrict__ w,
                                 unsigned short* __restrict__ wp5) {
    int o = blockIdx.x * 256 + threadIdx.x;
    if (o >= NG_ * 2 * 8 * 512) return;
    int j    = o & 7;
    int lane = (o >> 3) & 63;
    int mt   = (o >> 9) & 7;
    int kk   = (o >> 12) & 1;
    int g    = o >> 13;
    int q    = g / 9;
    int tap  = g - q * 9;
    int kout = mt * 32 + (lane & 31);
    int c    = q * 32 + kk * 16 + (lane >> 5) * 8 + j;
    wp5[o] = f2bf(w[(kout * C_ + c) * 9 + tap]);
}

// ---------------- x prepack: NCHW fp32 -> padded NHWC bf16 -----------------
__global__ void pack_x_kernel(const float* __restrict__ x,
                              unsigned short* __restrict__ xp) {
    __shared__ unsigned short Lt[128 * 57];
    const int t  = threadIdx.x;               // 256
    const int b  = blockIdx.x;                // n*58 + hp
    const int n  = b / HP_;
    const int hp = b - n * HP_;
    unsigned short* orow = xp + ((size_t)(n * HP_ + hp) * HP_) * 128;

    ushort8 z = {0, 0, 0, 0, 0, 0, 0, 0};
    if (hp == 0 || hp == HP_ - 1) {
        for (int u = t; u < 928; u += 256)
            *(ushort8*)(orow + u * 8) = z;
        return;
    }
    const int h = hp - 1;
    const float* src = x + ((size_t)n * C_ * HW_ + h * W_);
    #pragma unroll
    for (int k = 0; k < 28; ++k) {
        int idx = k * 256 + t;
        int c = idx / 56, w2 = idx - 56 * c;
        Lt[c * 57 + w2] = f2bf(src[c * HW_ + w2]);
    }
    __syncthreads();
    for (int u = t; u < 928; u += 256) {
        int wp = u >> 4, c8 = u & 15;
        ushort8 v = z;
        if (wp >= 1 && wp <= 56) {
            #pragma unroll
            for (int j = 0; j < 8; ++j)
                v[j] = Lt[(c8 * 8 + j) * 57 + (wp - 1)];
        }
        *(ushort8*)(orow + u * 8) = v;
    }
}

// ---------------- main conv: 32x32 frags, zero-dup A, matrix-bound ---------
// Block: 256 kout x 128 flat px, 256 thr / 4 waves, M-only split:
// wave = 64 kout x 128 px (mi=2, ni=4, kk=2; acc = 2x4 f32x16 = 128 regs).
// A: each wave owns distinct kout -> weights read exactly once per block
// (451 MB L2 total, parity-prefetched). B: window = 8 consecutive xp rows x
// 32 ch, plane-major [slot4][col], linear DMA dest + (slot=u/PLANE_,
// col=u%PLANE_) source (R19-verified); reads = 32-lane consecutive 512B runs
// (conflict-free). B-reuse=2 -> LDS port 17.6us < matrix 23.7us. Ring-2,
// stage-at-top, counted vmcnt(4), setprio. launch_bounds(256,2): 256-VGPR
// budget, 2 blocks/CU.
__launch_bounds__(256, 2)
__global__ void conv_mfma19_kernel(const unsigned short* __restrict__ xp,
                                   const unsigned short* __restrict__ wp5,
                                   const float* __restrict__ bias,
                                   float* __restrict__ out) {
    __shared__ __align__(16) unsigned char Bl[2][2048 * 16];   // 64 KB

    const int t    = threadIdx.x;
    const int lane = t & 63;
    const int wid  = t >> 6;     // 0..3 : 64-kout group
    const int l5   = lane >> 5;  // k-subgroup 0..1
    const int lc   = lane & 31;  // px-in-fragment

    // bijective XCD swizzle (784 % 8 == 0): 98 contiguous blocks per XCD
    const int b    = blockIdx.x;
    const int orig = (b & 7) * 98 + (b >> 3);
    const int px0  = orig * 128;

    // window base row (global padded-row index; rows contiguous across images)
    const int n0 = px0 / HW_;
    const int h0 = (px0 - n0 * HW_) / W_;
    const int G0 = n0 * HP_ + h0;

    // per-lane B column bases (tap adds r*58 + s)
    int cbase[4];
    #pragma unroll
    for (int ni = 0; ni < 4; ++ni) {
        int px = px0 + ni * 32 + lc;
        int n  = px / HW_;
        int pr = px - n * HW_;
        int h  = pr / W_;
        int w2 = pr - W_ * h;
        cbase[ni] = (n * HP_ + h - G0) * HP_ + w2;
    }

    // B read byte offsets: plane = kk*2 + l5
    int bunit[2][4];
    #pragma unroll
    for (int kk = 0; kk < 2; ++kk)
        #pragma unroll
        for (int ni = 0; ni < 4; ++ni)
            bunit[kk][ni] = ((kk * 2 + l5) * PLANE_ + cbase[ni]) * 16;

    // staging: 8 DMAs/thread; linear dest unit u realizes [slot][col] via
    // source (slot = u/PLANE_, col = u%PLANE_). Clamped slots/cols land in
    // pad units that are never read. Element offsets precomputed.
    int soff[8];
    #pragma unroll
    for (int i = 0; i < 8; ++i) {
        int u    = i * 256 + t;
        int slot = u / PLANE_;                 // 0..4
        int col  = u - slot * PLANE_;
        bool ok  = (slot < 4) && (col < COLS_);
        int ssl  = ok ? slot : 0;
        int scol = ok ? col : 0;
        int sidx = G0 * HP_ + scol;
        if (sidx > MAXROW_) sidx = 0;          // never-read clamp (tail blocks)
        soff[i] = sidx * 128 + ssl * 8;
    }

    const ushort8* W8 = (const ushort8*)wp5;

    f32x16 acc[2][4];   // [mi][ni]
    #pragma unroll
    for (int mi = 0; mi < 2; ++mi)
        #pragma unroll
        for (int ni = 0; ni < 4; ++ni)
            #pragma unroll
            for (int r = 0; r < 16; ++r)
                acc[mi][ni][r] = 0.f;

    bf16x8 areg[2][2][2];   // [parity][kk][mi]

#define STAGE(CC, BUF)                                                      \
    _Pragma("unroll")                                                       \
    for (int i = 0; i < 8; ++i)                                             \
        dma16(xp + soff[i] + (CC) * 32, Bl[BUF] + (size_t)(i * 256 + t) * 16);

#define LOAD_A(G, PAR)                                                      \
    _Pragma("unroll")                                                       \
    for (int kk = 0; kk < 2; ++kk)                                          \
        _Pragma("unroll")                                                   \
        for (int mi = 0; mi < 2; ++mi)                                      \
            areg[PAR][kk][mi] = __builtin_bit_cast(bf16x8,                  \
                W8[(((G) * 2 + kk) * 8 + (wid * 2 + mi)) * 64 + lane]);

    // one tap step; P compile-time (rule #20), CCV may be runtime
#define TAP_BODY(CCV, TAP, P, BUF)                                          \
    {                                                                       \
        const int SH = (((TAP) / 3) * HP_ + ((TAP) % 3)) * 16;              \
        bf16x8 bb[2][4];                                                    \
        _Pragma("unroll")                                                   \
        for (int kk = 0; kk < 2; ++kk)                                      \
            _Pragma("unroll")                                               \
            for (int ni = 0; ni < 4; ++ni)                                  \
                bb[kk][ni] = __builtin_bit_cast(bf16x8,                     \
                    *(const ushort8*)(Bl[BUF] + bunit[kk][ni] + SH));       \
        const int gnext = (CCV) * 9 + (TAP) + 1;                            \
        if (gnext < NG_) { LOAD_A(gnext, (P) ^ 1) }                         \
        __builtin_amdgcn_s_setprio(1);                                      \
        _Pragma("unroll")                                                   \
        for (int kk = 0; kk < 2; ++kk)                                      \
            _Pragma("unroll")                                               \
            for (int ni = 0; ni < 4; ++ni)                                  \
                _Pragma("unroll")                                           \
                for (int mi = 0; mi < 2; ++mi)                              \
                    acc[mi][ni] = __builtin_amdgcn_mfma_f32_32x32x16_bf16(  \
                        areg[P][kk][mi], bb[kk][ni], acc[mi][ni], 0, 0, 0); \
        __builtin_amdgcn_s_setprio(0);                                      \
    }

    // one chunk: stage next at top, 9 taps, counted-vmcnt barrier
#define CHUNK(CCV, P0, BUF)                                                 \
    {                                                                       \
        if ((CCV) < 3) { STAGE((CCV) + 1, (BUF) ^ 1) }                      \
        TAP_BODY(CCV, 0, P0, BUF)       TAP_BODY(CCV, 1, (P0)^1, BUF)       \
        TAP_BODY(CCV, 2, P0, BUF)       TAP_BODY(CCV, 3, (P0)^1, BUF)       \
        TAP_BODY(CCV, 4, P0, BUF)       TAP_BODY(CCV, 5, (P0)^1, BUF)       \
        TAP_BODY(CCV, 6, P0, BUF)       TAP_BODY(CCV, 7, (P0)^1, BUF)       \
        TAP_BODY(CCV, 8, P0, BUF)                                           \
        if ((CCV) < 3) {                                                    \
            asm volatile("s_waitcnt vmcnt(4)" ::: "memory");                \
            __builtin_amdgcn_s_barrier();                                   \
        }                                                                   \
    }

    // prologue
    LOAD_A(0, 0)
    STAGE(0, 0)
    asm volatile("s_waitcnt vmcnt(0)" ::: "memory");
    __builtin_amdgcn_s_barrier();

    #pragma unroll 1
    for (int c2 = 0; c2 < 2; ++c2) {
        const int cc0 = 2 * c2;
        CHUNK(cc0, 0, 0)
        CHUNK(cc0 + 1, 1, 1)
    }
#undef CHUNK
#undef TAP_BODY
#undef STAGE
#undef LOAD_A

    // epilogue: C/D 32x32 (verified): col(px)=lane&31,
    // row(kout) = (r&3) + 8*(r>>2) + 4*(lane>>5)
    #pragma unroll
    for (int ni = 0; ni < 4; ++ni) {
        int px = px0 + ni * 32 + lc;
        int n2 = px / HW_;
        int pr = px - n2 * HW_;
        float* ob = out + (size_t)n2 * K_ * HW_ + pr;
        #pragma unroll
        for (int mi = 0; mi < 2; ++mi) {
            const int kb = (wid * 2 + mi) * 32;
            #pragma unroll
            for (int r = 0; r < 16; ++r) {
                int kout = kb + (r & 3) + 8 * (r >> 2) + 4 * l5;
                ob[(size_t)kout * HW_] = acc[mi][ni][r] + bias[kout];
            }
        }
    }
}

// ---------------- fallback (reg-staged fp32 path, no workspace xp) ---------
__global__ void repack_w2_kernel(const float* __restrict__ w,
                                 unsigned short* __restrict__ wp2) {
    int o = blockIdx.x * 256 + threadIdx.x;
    if (o >= 9 * 16 * 4 * 64 * 8) return;
    int j   = o & 7;
    int l   = (o >> 3) & 63;
    int cc  = (o >> 9) & 3;
    int kg  = (o >> 11) & 15;
    int tap = o >> 15;
    int k = kg * 16 + (l & 15);
    int c = cc * 32 + (l >> 4) * 8 + j;
    wp2[o] = f2bf(w[(k * C_ + c) * 9 + tap]);
}

__launch_bounds__(256, 2)
__global__ void conv_mfma3_kernel(const float* __restrict__ x,
                                  const unsigned short* __restrict__ wp2,
                                  const float* __restrict__ bias,
                                  float* __restrict__ out) {
    __shared__ unsigned short Xt[2][232 * 40];
    const int t    = threadIdx.x;
    const int lane = t & 63;
    const int wid  = t >> 6;
    const int b    = blockIdx.x;
    const int orig = (b & 7) * 112 + (b >> 3);
    const int n    = orig / 28;
    const int rp   = orig - n * 28;
    const int h0   = rp * 2;
    const int lp = lane & 15;
    const int lk = lane >> 4;
    int bofs[7];
    #pragma unroll
    for (int ni = 0; ni < 7; ++ni) {
        int p  = ni * 16 + lp;
        int hr = (p >= 56) ? 1 : 0;
        int pw = p - hr * 56;
        bofs[ni] = (hr * 58 + pw) * 40 + lk * 8;
    }
    bool  ok[4], v928[4];
    const float* xq[4];
    int   ldsw[4];
    #pragma unroll
    for (int i = 0; i < 4; ++i) {
        int it = i * 256 + t;
        v928[i] = (it < 928);
        int itc  = v928[i] ? it : 0;
        int csub = (itc >= 232) + (itc >= 464) + (itc >= 696);
        int col  = itc - 232 * csub;
        int hh   = col / 58;
        int ww   = col - 58 * hh;
        int hin  = h0 + hh - 1;
        int win  = ww - 1;
        ok[i]   = v928[i] && (unsigned)hin < 56u && (unsigned)win < 56u;
        xq[i]   = x + (((n * C_ + csub * 8) * H_ + hin) * W_ + win);
        ldsw[i] = col * 40 + csub * 8;
    }
    float xv[4][8];
#define STAGE_LOAD(CH)                                                 \
    _Pragma("unroll")                                                  \
    for (int i = 0; i < 4; ++i)                                        \
        _Pragma("unroll")                                              \
        for (int j = 0; j < 8; ++j)                                    \
            xv[i][j] = ok[i] ? xq[i][((CH) * 32 + j) * HW_] : 0.f;
#define STAGE_WRITE(BUF)                                               \
    _Pragma("unroll")                                                  \
    for (int i = 0; i < 4; ++i)                                        \
        if (v928[i]) {                                                 \
            ushort8 v;                                                 \
            _Pragma("unroll")                                          \
            for (int j = 0; j < 8; ++j) v[j] = f2bf(xv[i][j]);         \
            *(ushort8*)(&Xt[BUF][ldsw[i]]) = v;                        \
        }
    f32x4 acc[4][7];
    #pragma unroll
    for (int mi = 0; mi < 4; ++mi)
        #pragma unroll
        for (int ni = 0; ni < 7; ++ni)
            acc[mi][ni] = (f32x4){0.f, 0.f, 0.f, 0.f};
    STAGE_LOAD(0)
    STAGE_WRITE(0)
    __syncthreads();
    const ushort8* W8 = (const ushort8*)wp2;
    for (int cc = 0; cc < 4; ++cc) {
        const int cur = cc & 1;
        if (cc < 3) { STAGE_LOAD(cc + 1) }
        const int tb = wid * 1024 + cc * 64 + lane;
        #pragma unroll
        for (int tap = 0; tap < 9; ++tap) {
            const int r    = tap / 3;
            const int s    = tap - 3 * r;
            const int toff = (r * 58 + s) * 40;
            bf16x8 a[4];
            #pragma unroll
            for (int mi = 0; mi < 4; ++mi)
                a[mi] = __builtin_bit_cast(bf16x8, W8[tap * 4096 + tb + mi * 256]);
            bf16x8 bfr[7];
            #pragma unroll
            for (int ni = 0; ni < 7; ++ni)
                bfr[ni] = __builtin_bit_cast(bf16x8,
                    *(const ushort8*)(&Xt[cur][bofs[ni] + toff]));
            #pragma unroll
            for (int ni = 0; ni < 7; ++ni)
                #pragma unroll
                for (int mi = 0; mi < 4; ++mi)
                    acc[mi][ni] = __builtin_amdgcn_mfma_f32_16x16x32_bf16(
                        a[mi], bfr[ni], acc[mi][ni], 0, 0, 0);
        }
        if (cc < 3) {
            STAGE_WRITE(cur ^ 1)
            __syncthreads();
        }
    }
    #pragma unroll
    for (int mi = 0; mi < 4; ++mi) {
        #pragma unroll
        for (int j = 0; j < 4; ++j) {
            int kout = wid * 64 + mi * 16 + lk * 4 + j;
            float bv = bias[kout];
            float* op = out + ((n * K_ + kout) * H_ + h0) * W_;
            #pragma unroll
            for (int ni = 0; ni < 7; ++ni) {
                int p  = ni * 16 + lp;
                int hr = (p >= 56) ? 1 : 0;
                int pw = p - hr * 56;
                op[hr * W_ + pw] = acc[mi][ni][j] + bv;
            }
        }
    }
#undef STAGE_LOAD
#undef STAGE_WRITE
}

__global__ void conv_naive_kernel(const float* __restrict__ x,
                                  const float* __restrict__ w,
                                  const float* __restrict__ b,
                                  float* __restrict__ out) {
    int idx = blockIdx.x * 256 + threadIdx.x;
    if (idx >= N_ * K_ * HW_) return;
    int pw = idx % 56; int tmp = idx / 56;
    int h  = tmp % 56; tmp /= 56;
    int k  = tmp % 256; int n = tmp / 256;
    float acc = b[k];
    for (int c = 0; c < C_; ++c)
        for (int r = 0; r < 3; ++r) {
            int hin = h + r - 1;
            if ((unsigned)hin >= 56u) continue;
            for (int s = 0; s < 3; ++s) {
                int win = pw + s - 1;
                if ((unsigned)win >= 56u) continue;
                acc += x[((n * C_ + c) * H_ + hin) * W_ + win] * w[(k * C_ + c) * 9 + r * 3 + s];
            }
        }
    out[idx] = acc;
}

extern "C" void kernel_launch(void* const* d_in, const int* in_sizes, int n_in,
                              void* d_out, int out_size, void* d_ws, size_t ws_size,
                              hipStream_t stream) {
    const float* x = (const float*)d_in[0];
    const float* w = (const float*)d_in[1];
    const float* b = (const float*)d_in[2];
    float* out = (float*)d_out;

    const size_t xp_bytes = (size_t)N_ * HP_ * HP_ * C_ * 2;              // 27,557,888
    const size_t wp_bytes = (size_t)NG_ * 2 * 8 * 512 * 2;                // 589,824

    if (ws_size >= xp_bytes + wp_bytes) {
        unsigned short* xpad = (unsigned short*)d_ws;
        unsigned short* wp5  = (unsigned short*)((char*)d_ws + xp_bytes);
        pack_x_kernel<<<N_ * HP_, 256, 0, stream>>>(x, xpad);
        repack_w5_kernel<<<(NG_ * 2 * 8 * 512 + 255) / 256, 256, 0, stream>>>(w, wp5);
        conv_mfma19_kernel<<<784, 256, 0, stream>>>(xpad, wp5, b, out);
    } else if (ws_size >= wp_bytes) {
        unsigned short* wp2 = (unsigned short*)d_ws;
        repack_w2_kernel<<<(9 * 16 * 4 * 64 * 8 + 255) / 256, 256, 0, stream>>>(w, wp2);
        conv_mfma3_kernel<<<896, 256, 0, stream>>>(x, wp2, b, out);
    } else {
        conv_naive_kernel<<<(N_ * K_ * HW_ + 255) / 256, 256, 0, stream>>>(x, w, b, out);
    }
}

// Round 21
// 77.360 us; speedup vs baseline: 1.6568x; 1.4076x over previous
//
#include <hip/hip_runtime.h>
#include <hip/hip_bf16.h>

#define N_ 32
#define C_ 128
#define H_ 56
#define W_ 56
#define K_ 256
#define HW_ (H_*W_)
#define HP_ 58   // padded spatial dim
#define PL_ 234  // LDS plane stride in 16B units

typedef __attribute__((ext_vector_type(8))) __bf16 bf16x8;
typedef __attribute__((ext_vector_type(8))) unsigned short ushort8;
typedef __attribute__((ext_vector_type(4))) float f32x4;

typedef __attribute__((address_space(1))) const unsigned int g1_u32;
typedef __attribute__((address_space(3))) unsigned int l3_u32;

__device__ __forceinline__ void dma16(const void* g, void* l) {
    __builtin_amdgcn_global_load_lds((g1_u32*)g, (l3_u32*)l, 16, 0, 0);
}

__device__ __forceinline__ unsigned short f2bf(float f) {
    unsigned int u = __builtin_bit_cast(unsigned int, f);
    u += 0x7FFFu + ((u >> 16) & 1u);   // round-to-nearest-even
    return (unsigned short)(u >> 16);
}

// ---------------- weight repack: OIHW fp32 -> fragment-major bf16 ----------
// wp2[((tap*16 + kg)*4 + cc)*64 + lane][j]: k = kg*16+(lane&15), c = cc*32+(lane>>4)*8+j
__global__ void repack_w2_kernel(const float* __restrict__ w,
                                 unsigned short* __restrict__ wp2) {
    int o = blockIdx.x * 256 + threadIdx.x;
    if (o >= 9 * 16 * 4 * 64 * 8) return;
    int j   = o & 7;
    int l   = (o >> 3) & 63;
    int cc  = (o >> 9) & 3;
    int kg  = (o >> 11) & 15;
    int tap = o >> 15;
    int k = kg * 16 + (l & 15);
    int c = cc * 32 + (l >> 4) * 8 + j;
    wp2[o] = f2bf(w[(k * C_ + c) * 9 + tap]);
}

// ---------------- x prepack: NCHW fp32 -> padded NHWC bf16 -----------------
__global__ void pack_x_kernel(const float* __restrict__ x,
                              unsigned short* __restrict__ xp) {
    __shared__ unsigned short Lt[128 * 57];
    const int t  = threadIdx.x;               // 256
    const int b  = blockIdx.x;                // n*58 + hp
    const int n  = b / HP_;
    const int hp = b - n * HP_;
    unsigned short* orow = xp + ((size_t)(n * HP_ + hp) * HP_) * 128;

    ushort8 z = {0, 0, 0, 0, 0, 0, 0, 0};
    if (hp == 0 || hp == HP_ - 1) {
        for (int u = t; u < 928; u += 256)
            *(ushort8*)(orow + u * 8) = z;
        return;
    }
    const int h = hp - 1;
    const float* src = x + ((size_t)n * C_ * HW_ + h * W_);
    #pragma unroll
    for (int k = 0; k < 28; ++k) {
        int idx = k * 256 + t;
        int c = idx / 56, w2 = idx - 56 * c;
        Lt[c * 57 + w2] = f2bf(src[c * HW_ + w2]);
    }
    __syncthreads();
    for (int u = t; u < 928; u += 256) {
        int wp = u >> 4, c8 = u & 15;
        ushort8 v = z;
        if (wp >= 1 && wp <= 56) {
            #pragma unroll
            for (int j = 0; j < 8; ++j)
                v[j] = Lt[(c8 * 8 + j) * 57 + (wp - 1)];
        }
        *(ushort8*)(orow + u * 8) = v;
    }
}

// ---------------- main conv: champion (R15) — mi=2, 12 waves/CU ------------
// Block: 128 kout x 112 px (2 rows), 4 waves, each wave 32 kout x 112 px
// (mi=2, ni=7, acc=56). Grid 1792. 3-buffer B ring (48 KB) -> 3 blocks/CU
// at launch_bounds(256,3) => 12 waves/CU (3/SIMD). Per chunk: 63 B ds_reads
// + per-tap A-parity-prefetch from L2 + 126 MFMA; counted vmcnt, 3 barriers.
__launch_bounds__(256, 3)
__global__ void conv_mfma14_kernel(const unsigned short* __restrict__ xp,
                                   const unsigned short* __restrict__ wp2,
                                   const float* __restrict__ bias,
                                   float* __restrict__ out) {
    __shared__ __align__(16) unsigned char Xt[3][16384];

    const int t    = threadIdx.x;
    const int lane = t & 63;
    const int wid  = t >> 6;

    // bijective XCD swizzle (1792 % 8 == 0): 224 contiguous blocks per XCD
    const int b    = blockIdx.x;
    const int orig = (b & 7) * 224 + (b >> 3);
    const int kb   = orig & 1;          // 128-kout half
    const int cell = orig >> 1;         // consecutive origs share x-window
    const int n    = cell / 28;
    const int rp   = cell - n * 28;
    const int h0   = rp * 2;

    const int lp = lane & 15;
    const int lk = lane >> 4;

    // B-fragment byte offsets (tap adds (r*58+s)*16)
    int bunit[7];
    #pragma unroll
    for (int ni = 0; ni < 7; ++ni) {
        int p  = ni * 16 + lp;
        int hr = (p >= 56) ? 1 : 0;
        int pw = p - hr * 56;
        bunit[ni] = (lk * PL_ + hr * HP_ + pw) * 16;
    }

    // staging geometry: slot u = i*256+t -> (csub,col) = (u/PL_, u%PL_);
    // invalid slots clamp source to xp base (garbage lands in pad units).
    const unsigned short* gsrc[4];
    #pragma unroll
    for (int i = 0; i < 4; ++i) {
        int u    = i * 256 + t;
        int csub = u / PL_;
        int col  = u - PL_ * csub;
        bool ok  = (csub < 4) && (col < 232);
        int csc  = ok ? csub : 0;
        int colc = ok ? col : 0;
        int hh   = colc / HP_;
        int ww   = colc - HP_ * hh;
        gsrc[i]  = ok ? xp + (((size_t)(n * HP_ + h0 + hh) * HP_ + ww) * 128 + csc * 8)
                      : xp;
    }

    f32x4 acc[2][7];
    #pragma unroll
    for (int mi = 0; mi < 2; ++mi)
        #pragma unroll
        for (int ni = 0; ni < 7; ++ni)
            acc[mi][ni] = (f32x4){0.f, 0.f, 0.f, 0.f};

    const ushort8* W8 = (const ushort8*)wp2;
    const int kgbase = kb * 8 + wid * 2;   // wave owns kout [kgbase*16, +32)
    bf16x8 areg[2][2];                     // [parity][mi]

#define STAGE(CH, BUF)                                                     \
    _Pragma("unroll")                                                      \
    for (int i = 0; i < 4; ++i)                                            \
        dma16(gsrc[i] + (CH) * 32, Xt[BUF] + i * 4096 + wid * 1024);

#define LOAD_A(TAP, CC, PAR)                                               \
    _Pragma("unroll")                                                      \
    for (int mi = 0; mi < 2; ++mi)                                         \
        areg[PAR][mi] = __builtin_bit_cast(bf16x8,                         \
            W8[(TAP) * 4096 + ((kgbase + mi) * 4 + (CC)) * 64 + lane]);

    // prologue: A(0) first (earliest L2 issue), then DMA chunks 0,1
    LOAD_A(0, 0, 0)
    STAGE(0, 0)
    STAGE(1, 1)
    asm volatile("s_waitcnt vmcnt(4)" ::: "memory");   // A(0)+buf0 landed
    __builtin_amdgcn_s_barrier();

    #pragma unroll
    for (int cc = 0; cc < 4; ++cc) {
        const int cur = cc % 3;

        #pragma unroll
        for (int tap = 0; tap < 9; ++tap) {
            const int g = cc * 9 + tap;     // global tap index (compile-time)
            const int p = g & 1;

            const int r    = tap / 3;
            const int s    = tap - 3 * r;
            const int toff = (r * HP_ + s) * 16;

            bf16x8 bfr[7];
            #pragma unroll
            for (int ni = 0; ni < 7; ++ni)
                bfr[ni] = __builtin_bit_cast(bf16x8,
                    *(const ushort8*)(Xt[cur] + bunit[ni] + toff));

            // prefetch A for global tap g+1 (crosses chunk boundary freely)
            if (g + 1 < 36) {
                const int nc = (g + 1) / 9;
                const int nt = (g + 1) - nc * 9;
                LOAD_A(nt, nc, p ^ 1)
            }

            __builtin_amdgcn_s_setprio(1);
            #pragma unroll
            for (int ni = 0; ni < 7; ++ni)
                #pragma unroll
                for (int mi = 0; mi < 2; ++mi)
                    acc[mi][ni] = __builtin_amdgcn_mfma_f32_16x16x32_bf16(
                        areg[p][mi], bfr[ni], acc[mi][ni], 0, 0, 0);
            __builtin_amdgcn_s_setprio(0);
        }

        if (cc < 2) { STAGE(cc + 2, (cc + 2) % 3) }    // newest vmem ops

        if (cc < 3) {
            // keep stage(cc+2) [if any] + A-prefetch(2) in flight
            if (cc < 2) asm volatile("s_waitcnt vmcnt(6)" ::: "memory");
            else        asm volatile("s_waitcnt vmcnt(2)" ::: "memory");
            __builtin_amdgcn_s_barrier();
        }
    }
#undef STAGE
#undef LOAD_A

    // epilogue: bias + fp32 store
    #pragma unroll
    for (int mi = 0; mi < 2; ++mi) {
        #pragma unroll
        for (int j = 0; j < 4; ++j) {
            int kout = kb * 128 + wid * 32 + mi * 16 + lk * 4 + j;
            float bv = bias[kout];
            float* op = out + ((n * K_ + kout) * H_ + h0) * W_;
            #pragma unroll
            for (int ni = 0; ni < 7; ++ni) {
                int p  = ni * 16 + lp;
                int hr = (p >= 56) ? 1 : 0;
                int pw = p - hr * 56;
                op[hr * W_ + pw] = acc[mi][ni][j] + bv;
            }
        }
    }
}

// ---------------- fallback (reg-staged fp32 path, no workspace xp) ---------
__launch_bounds__(256, 2)
__global__ void conv_mfma3_kernel(const float* __restrict__ x,
                                  const unsigned short* __restrict__ wp2,
                                  const float* __restrict__ bias,
                                  float* __restrict__ out) {
    __shared__ unsigned short Xt[2][232 * 40];
    const int t    = threadIdx.x;
    const int lane = t & 63;
    const int wid  = t >> 6;
    const int b    = blockIdx.x;
    const int orig = (b & 7) * 112 + (b >> 3);
    const int n    = orig / 28;
    const int rp   = orig - n * 28;
    const int h0   = rp * 2;
    const int lp = lane & 15;
    const int lk = lane >> 4;
    int bofs[7];
    #pragma unroll
    for (int ni = 0; ni < 7; ++ni) {
        int p  = ni * 16 + lp;
        int hr = (p >= 56) ? 1 : 0;
        int pw = p - hr * 56;
        bofs[ni] = (hr * 58 + pw) * 40 + lk * 8;
    }
    bool  ok[4], v928[4];
    const float* xq[4];
    int   ldsw[4];
    #pragma unroll
    for (int i = 0; i < 4; ++i) {
        int it = i * 256 + t;
        v928[i] = (it < 928);
        int itc  = v928[i] ? it : 0;
        int csub = (itc >= 232) + (itc >= 464) + (itc >= 696);
        int col  = itc - 232 * csub;
        int hh   = col / 58;
        int ww   = col - 58 * hh;
        int hin  = h0 + hh - 1;
        int win  = ww - 1;
        ok[i]   = v928[i] && (unsigned)hin < 56u && (unsigned)win < 56u;
        xq[i]   = x + (((n * C_ + csub * 8) * H_ + hin) * W_ + win);
        ldsw[i] = col * 40 + csub * 8;
    }
    float xv[4][8];
#define STAGE_LOAD(CH)                                                 \
    _Pragma("unroll")                                                  \
    for (int i = 0; i < 4; ++i)                                        \
        _Pragma("unroll")                                              \
        for (int j = 0; j < 8; ++j)                                    \
            xv[i][j] = ok[i] ? xq[i][((CH) * 32 + j) * HW_] : 0.f;
#define STAGE_WRITE(BUF)                                               \
    _Pragma("unroll")                                                  \
    for (int i = 0; i < 4; ++i)                                        \
        if (v928[i]) {                                                 \
            ushort8 v;                                                 \
            _Pragma("unroll")                                          \
            for (int j = 0; j < 8; ++j) v[j] = f2bf(xv[i][j]);         \
            *(ushort8*)(&Xt[BUF][ldsw[i]]) = v;                        \
        }
    f32x4 acc[4][7];
    #pragma unroll
    for (int mi = 0; mi < 4; ++mi)
        #pragma unroll
        for (int ni = 0; ni < 7; ++ni)
            acc[mi][ni] = (f32x4){0.f, 0.f, 0.f, 0.f};
    STAGE_LOAD(0)
    STAGE_WRITE(0)
    __syncthreads();
    const ushort8* W8 = (const ushort8*)wp2;
    for (int cc = 0; cc < 4; ++cc) {
        const int cur = cc & 1;
        if (cc < 3) { STAGE_LOAD(cc + 1) }
        const int tb = wid * 1024 + cc * 64 + lane;
        #pragma unroll
        for (int tap = 0; tap < 9; ++tap) {
            const int r    = tap / 3;
            const int s    = tap - 3 * r;
            const int toff = (r * 58 + s) * 40;
            bf16x8 a[4];
            #pragma unroll
            for (int mi = 0; mi < 4; ++mi)
                a[mi] = __builtin_bit_cast(bf16x8, W8[tap * 4096 + tb + mi * 256]);
            bf16x8 bfr[7];
            #pragma unroll
            for (int ni = 0; ni < 7; ++ni)
                bfr[ni] = __builtin_bit_cast(bf16x8,
                    *(const ushort8*)(&Xt[cur][bofs[ni] + toff]));
            #pragma unroll
            for (int ni = 0; ni < 7; ++ni)
                #pragma unroll
                for (int mi = 0; mi < 4; ++mi)
                    acc[mi][ni] = __builtin_amdgcn_mfma_f32_16x16x32_bf16(
                        a[mi], bfr[ni], acc[mi][ni], 0, 0, 0);
        }
        if (cc < 3) {
            STAGE_WRITE(cur ^ 1)
            __syncthreads();
        }
    }
    #pragma unroll
    for (int mi = 0; mi < 4; ++mi) {
        #pragma unroll
        for (int j = 0; j < 4; ++j) {
            int kout = wid * 64 + mi * 16 + lk * 4 + j;
            float bv = bias[kout];
            float* op = out + ((n * K_ + kout) * H_ + h0) * W_;
            #pragma unroll
            for (int ni = 0; ni < 7; ++ni) {
                int p  = ni * 16 + lp;
                int hr = (p >= 56) ? 1 : 0;
                int pw = p - hr * 56;
                op[hr * W_ + pw] = acc[mi][ni][j] + bv;
            }
        }
    }
#undef STAGE_LOAD
#undef STAGE_WRITE
}

__global__ void conv_naive_kernel(const float* __restrict__ x,
                                  const float* __restrict__ w,
                                  const float* __restrict__ b,
                                  float* __restrict__ out) {
    int idx = blockIdx.x * 256 + threadIdx.x;
    if (idx >= N_ * K_ * HW_) return;
    int pw = idx % 56; int tmp = idx / 56;
    int h  = tmp % 56; tmp /= 56;
    int k  = tmp % 256; int n = tmp / 256;
    float acc = b[k];
    for (int c = 0; c < C_; ++c)
        for (int r = 0; r < 3; ++r) {
            int hin = h + r - 1;
            if ((unsigned)hin >= 56u) continue;
            for (int s = 0; s < 3; ++s) {
                int win = pw + s - 1;
                if ((unsigned)win >= 56u) continue;
                acc += x[((n * C_ + c) * H_ + hin) * W_ + win] * w[(k * C_ + c) * 9 + r * 3 + s];
            }
        }
    out[idx] = acc;
}

extern "C" void kernel_launch(void* const* d_in, const int* in_sizes, int n_in,
                              void* d_out, int out_size, void* d_ws, size_t ws_size,
                              hipStream_t stream) {
    const float* x = (const float*)d_in[0];
    const float* w = (const float*)d_in[1];
    const float* b = (const float*)d_in[2];
    float* out = (float*)d_out;

    const size_t xp_bytes = (size_t)N_ * HP_ * HP_ * C_ * 2;              // 27,557,888
    const size_t wp_bytes = (size_t)9 * 16 * 4 * 64 * 8 * 2;              // 589,824

    if (ws_size >= xp_bytes + wp_bytes) {
        unsigned short* xpad = (unsigned short*)d_ws;
        unsigned short* wp2  = (unsigned short*)((char*)d_ws + xp_bytes);
        pack_x_kernel<<<N_ * HP_, 256, 0, stream>>>(x, xpad);
        repack_w2_kernel<<<(9 * 16 * 4 * 64 * 8 + 255) / 256, 256, 0, stream>>>(w, wp2);
        conv_mfma14_kernel<<<1792, 256, 0, stream>>>(xpad, wp2, b, out);
    } else if (ws_size >= wp_bytes) {
        unsigned short* wp2 = (unsigned short*)d_ws;
        repack_w2_kernel<<<(9 * 16 * 4 * 64 * 8 + 255) / 256, 256, 0, stream>>>(w, wp2);
        conv_mfma3_kernel<<<896, 256, 0, stream>>>(x, wp2, b, out);
    } else {
        conv_naive_kernel<<<(N_ * K_ * HW_ + 255) / 256, 256, 0, stream>>>(x, w, b, out);
    }
}